// Round 2
// baseline (164.043 us; speedup 1.0000x reference)
//
#include <hip/hip_runtime.h>

#define N 4096
#define LOG2E 1.4426950408889634f

__device__ __forceinline__ float fast_exp2(float x) {
#if __has_builtin(__builtin_amdgcn_exp2f)
    return __builtin_amdgcn_exp2f(x);
#else
    return exp2f(x);
#endif
}

__device__ float block_reduce_sum(float v) {
    __shared__ float red[8];
    int lane = threadIdx.x & 63;
    int wid = threadIdx.x >> 6;
    #pragma unroll
    for (int off = 32; off; off >>= 1) v += __shfl_down(v, off, 64);
    if (lane == 0) red[wid] = v;
    __syncthreads();
    if (threadIdx.x == 0) {
        int nw = (int)(blockDim.x >> 6);
        float s = red[0];
        for (int w = 1; w < nw; ++w) s += red[w];
        red[0] = s;
    }
    __syncthreads();
    float r = red[0];
    __syncthreads();
    return r;
}

// K1: per-vector stats + coefficient arrays.
// xa[vec][j] = (x_j, a_j)   (j-side, a = c1*x^2)
// ma[vec][i] = (m_i, a_i)   (i-side, m = -2*c1*x)
__global__ void k_stats(const float* __restrict__ fused,
                        const float* __restrict__ s1,
                        const float* __restrict__ s2,
                        float2* __restrict__ xa,
                        float2* __restrict__ ma) {
    int vec = blockIdx.x;
    int b = vec / 3, k = vec % 3;
    const float* src = (k == 0 ? fused : (k == 1 ? s1 : s2)) + b * 16384;
    int tid = threadIdx.x;
    float v[16];
    float s = 0.f;
    #pragma unroll
    for (int t = 0; t < 16; ++t) { v[t] = src[tid + t * 256]; s += v[t]; }
    float total = block_reduce_sum(s);
    float mean = total * (1.0f / 4096.0f);
    float ssq = 0.f;
    #pragma unroll
    for (int t = 0; t < 16; ++t) { float d = v[t] - mean; ssq += d * d; }
    float tssq = block_reduce_sum(ssq);
    float stdv = sqrtf(tssq / 4095.0f);            // ddof=1
    float sigma = fminf(fmaxf(0.2f * stdv, 0.001f), 1.0f);
    float inv = 1.0f / (stdv + 1e-8f);
    float c1 = -0.5f * LOG2E / (sigma * sigma);
    float2* xav = xa + (size_t)vec * N;
    float2* mav = ma + (size_t)vec * N;
    #pragma unroll
    for (int t = 0; t < 16; ++t) {
        int i = tid + t * 256;
        float x = (v[t] - mean) * inv;
        float a = c1 * x * x;
        xav[i] = make_float2(x, a);
        mav[i] = make_float2(-2.0f * c1 * x, a);
    }
}

// K2: raw kernel-sum partials. Tasks t=0..9: t=b*5+p; p<3 marginal of vec b*3+p,
// p=3: joint(x,y1), p=4: joint(x,y2).
// Each thread owns IB=4 i-values (block covers 1024 i's, nib=4).
// grid = 10 * 4 * js, block 256. j-range split js ways.
__global__ void k_pdf(const float2* __restrict__ xa,
                      const float2* __restrict__ ma,
                      float* __restrict__ part, int js) {
    const int nib = 4;
    int bid = blockIdx.x;
    int t = bid / (nib * js);
    int rem = bid % (nib * js);
    int ib = rem / js, jsp = rem % js;
    int p = t % 5, b = t / 5;
    int jlen = N / js;
    int j0 = jsp * jlen, j1 = j0 + jlen;
    int ibase = ib * 1024 + threadIdx.x;

    float acc[4] = {0.f, 0.f, 0.f, 0.f};

    if (p < 3) {
        int v = b * 3 + p;
        const float2* xav = xa + (size_t)v * N;
        const float2* mav = ma + (size_t)v * N;
        float m[4], ai[4];
        #pragma unroll
        for (int u = 0; u < 4; ++u) {
            float2 q = mav[ibase + u * 256];
            m[u] = q.x; ai[u] = q.y;
        }
        #pragma unroll 4
        for (int j = j0; j < j1; ++j) {
            float2 xj = xav[j];
            #pragma unroll
            for (int u = 0; u < 4; ++u)
                acc[u] += fast_exp2(fmaf(m[u], xj.x, ai[u]) + xj.y);
        }
    } else {
        int vx = b * 3, vy = b * 3 + (p - 2);
        const float2* xav = xa + (size_t)vx * N;
        const float2* yav = xa + (size_t)vy * N;
        const float2* mxv = ma + (size_t)vx * N;
        const float2* myv = ma + (size_t)vy * N;
        float mx[4], my[4], C[4];
        #pragma unroll
        for (int u = 0; u < 4; ++u) {
            float2 qx = mxv[ibase + u * 256];
            float2 qy = myv[ibase + u * 256];
            mx[u] = qx.x; my[u] = qy.x; C[u] = qx.y + qy.y;
        }
        #pragma unroll 4
        for (int j = j0; j < j1; ++j) {
            float2 xj = xav[j];
            float2 yj = yav[j];
            float S = xj.y + yj.y;
            #pragma unroll
            for (int u = 0; u < 4; ++u) {
                float e = fmaf(my[u], yj.x, fmaf(mx[u], xj.x, C[u])) + S;
                acc[u] += fast_exp2(e);
            }
        }
    }
    #pragma unroll
    for (int u = 0; u < 4; ++u)
        part[((size_t)t * js + jsp) * N + ibase + u * 256] = acc[u];
}

// K3a: reduce j-split partials -> pdf (/N) + per-task sums. 10 blocks.
__global__ void k_reduce(const float* __restrict__ part, float* __restrict__ pdf,
                         float* __restrict__ sums, int js) {
    int t = blockIdx.x;
    float local = 0.f;
    for (int i = threadIdx.x; i < N; i += 256) {
        float s = 0.f;
        for (int q = 0; q < js; ++q) s += part[((size_t)t * js + q) * N + i];
        s *= (1.0f / N);
        pdf[(size_t)t * N + i] = s;
        local += s;
    }
    float tot = block_reduce_sum(local);
    if (threadIdx.x == 0) sums[t] = tot;
}

// K3b: per-combo MI partial. 4 blocks.
__global__ void k_mi2(const float* __restrict__ pdf, const float* __restrict__ sums,
                      float* __restrict__ mi) {
    int c = blockIdx.x;
    int b = c >> 1, pr = c & 1;
    int tj = b * 5 + 3 + pr;
    int tx = b * 5;
    int ty = b * 5 + 1 + pr;
    float inv_sj = 1.0f / (sums[tj] + 1e-10f);
    float inv_sx = 1.0f / (sums[tx] + 1e-10f);
    float inv_sy = 1.0f / (sums[ty] + 1e-10f);
    float local = 0.f;
    for (int i = threadIdx.x; i < N; i += 256) {
        float pj = pdf[(size_t)tj * N + i] * inv_sj;
        float px = pdf[(size_t)tx * N + i] * inv_sx;
        float py = pdf[(size_t)ty * N + i] * inv_sy;
        float ratio = (pj + 1e-10f) / (px * py + 1e-10f);
        ratio = fminf(fmaxf(ratio, 1e-10f), 1e10f);
        local += pj * __logf(ratio);
    }
    float tot = block_reduce_sum(local);
    if (threadIdx.x == 0) mi[c] = tot;
}

// K4: final. 1 tiny block.
__global__ void k_fin(const float* __restrict__ mi, float* __restrict__ out) {
    if (threadIdx.x == 0)
        out[0] = -((mi[0] + mi[1]) + (mi[2] + mi[3])) * 0.5f;
}

extern "C" void kernel_launch(void* const* d_in, const int* in_sizes, int n_in,
                              void* d_out, int out_size, void* d_ws, size_t ws_size,
                              hipStream_t stream) {
    const float* fused = (const float*)d_in[0];
    const float* s1    = (const float*)d_in[1];
    const float* s2    = (const float*)d_in[2];
    float* out = (float*)d_out;
    float* ws  = (float*)d_ws;

    // ws layout (floats)
    const size_t off_xa   = 0;                         // 6*N*2
    const size_t off_ma   = off_xa + 12 * (size_t)N;   // 6*N*2
    const size_t off_pdf  = off_ma + 12 * (size_t)N;   // 10*N
    const size_t off_sums = off_pdf + 10 * (size_t)N;  // 16
    const size_t off_mi   = off_sums + 16;             // 16
    const size_t off_part = off_mi + 16;               // 10*js*N

    int js = 32;
    while (js > 1 && (off_part + (size_t)10 * js * N) * 4 > ws_size) js >>= 1;

    float2* ws_xa   = (float2*)(ws + off_xa);
    float2* ws_ma   = (float2*)(ws + off_ma);
    float*  ws_pdf  = ws + off_pdf;
    float*  ws_sums = ws + off_sums;
    float*  ws_mi   = ws + off_mi;
    float*  ws_part = ws + off_part;

    k_stats<<<dim3(6), dim3(256), 0, stream>>>(fused, s1, s2, ws_xa, ws_ma);
    k_pdf<<<dim3(10 * 4 * js), dim3(256), 0, stream>>>(ws_xa, ws_ma, ws_part, js);
    k_reduce<<<dim3(10), dim3(256), 0, stream>>>(ws_part, ws_pdf, ws_sums, js);
    k_mi2<<<dim3(4), dim3(256), 0, stream>>>(ws_pdf, ws_sums, ws_mi);
    k_fin<<<dim3(1), dim3(64), 0, stream>>>(ws_mi, out);
}

// Round 3
// 60.837 us; speedup vs baseline: 2.6965x; 2.6965x over previous
//
#include <hip/hip_runtime.h>

#define N 4096
#define LOG2E 1.4426950408889634f

__device__ __forceinline__ float fast_exp2(float x) {
#if __has_builtin(__builtin_amdgcn_exp2f)
    return __builtin_amdgcn_exp2f(x);
#else
    return exp2f(x);
#endif
}

__device__ float block_reduce_sum(float v) {
    __shared__ float red[8];
    int lane = threadIdx.x & 63;
    int wid = threadIdx.x >> 6;
    #pragma unroll
    for (int off = 32; off; off >>= 1) v += __shfl_down(v, off, 64);
    if (lane == 0) red[wid] = v;
    __syncthreads();
    if (threadIdx.x == 0) {
        int nw = (int)(blockDim.x >> 6);
        float s = red[0];
        for (int w = 1; w < nw; ++w) s += red[w];
        red[0] = s;
    }
    __syncthreads();
    float r = red[0];
    __syncthreads();
    return r;
}

// K1: per-vector stats + coefficient arrays.
// xa[vec][j] = (x_j, a_j)   (j-side, a = c1*x^2)
// ma[vec][i] = (m_i, a_i)   (i-side, m = -2*c1*x)
__global__ void k_stats(const float* __restrict__ fused,
                        const float* __restrict__ s1,
                        const float* __restrict__ s2,
                        float2* __restrict__ xa,
                        float2* __restrict__ ma) {
    int vec = blockIdx.x;
    int b = vec / 3, k = vec % 3;
    const float* src = (k == 0 ? fused : (k == 1 ? s1 : s2)) + b * 16384;
    int tid = threadIdx.x;
    float v[16];
    float s = 0.f;
    #pragma unroll
    for (int t = 0; t < 16; ++t) { v[t] = src[tid + t * 256]; s += v[t]; }
    float total = block_reduce_sum(s);
    float mean = total * (1.0f / 4096.0f);
    float ssq = 0.f;
    #pragma unroll
    for (int t = 0; t < 16; ++t) { float d = v[t] - mean; ssq += d * d; }
    float tssq = block_reduce_sum(ssq);
    float stdv = sqrtf(tssq / 4095.0f);            // ddof=1
    float sigma = fminf(fmaxf(0.2f * stdv, 0.001f), 1.0f);
    float inv = 1.0f / (stdv + 1e-8f);
    float c1 = -0.5f * LOG2E / (sigma * sigma);
    float2* xav = xa + (size_t)vec * N;
    float2* mav = ma + (size_t)vec * N;
    #pragma unroll
    for (int t = 0; t < 16; ++t) {
        int i = tid + t * 256;
        float x = (v[t] - mean) * inv;
        float a = c1 * x * x;
        xav[i] = make_float2(x, a);
        mav[i] = make_float2(-2.0f * c1 * x, a);
    }
}

// K2: raw kernel-sum partials. Tasks t=0..9: t=b*5+p; p<3 marginal of vec b*3+p,
// p=3: joint(x,y1), p=4: joint(x,y2).
// Each thread owns IB=4 i-values (block covers 1024 i's, nib=4).
// grid = 10 * 4 * js, block 256. j-range split js ways.
__global__ void k_pdf(const float2* __restrict__ xa,
                      const float2* __restrict__ ma,
                      float* __restrict__ part, int js) {
    const int nib = 4;
    int bid = blockIdx.x;
    int t = bid / (nib * js);
    int rem = bid % (nib * js);
    int ib = rem / js, jsp = rem % js;
    int p = t % 5, b = t / 5;
    int jlen = N / js;
    int j0 = jsp * jlen, j1 = j0 + jlen;
    int ibase = ib * 1024 + threadIdx.x;

    float acc[4] = {0.f, 0.f, 0.f, 0.f};

    if (p < 3) {
        int v = b * 3 + p;
        const float2* xav = xa + (size_t)v * N;
        const float2* mav = ma + (size_t)v * N;
        float m[4], ai[4];
        #pragma unroll
        for (int u = 0; u < 4; ++u) {
            float2 q = mav[ibase + u * 256];
            m[u] = q.x; ai[u] = q.y;
        }
        #pragma unroll 4
        for (int j = j0; j < j1; ++j) {
            float2 xj = xav[j];
            #pragma unroll
            for (int u = 0; u < 4; ++u)
                acc[u] += fast_exp2(fmaf(m[u], xj.x, ai[u]) + xj.y);
        }
    } else {
        int vx = b * 3, vy = b * 3 + (p - 2);
        const float2* xav = xa + (size_t)vx * N;
        const float2* yav = xa + (size_t)vy * N;
        const float2* mxv = ma + (size_t)vx * N;
        const float2* myv = ma + (size_t)vy * N;
        float mx[4], my[4], C[4];
        #pragma unroll
        for (int u = 0; u < 4; ++u) {
            float2 qx = mxv[ibase + u * 256];
            float2 qy = myv[ibase + u * 256];
            mx[u] = qx.x; my[u] = qy.x; C[u] = qx.y + qy.y;
        }
        #pragma unroll 4
        for (int j = j0; j < j1; ++j) {
            float2 xj = xav[j];
            float2 yj = yav[j];
            float S = xj.y + yj.y;
            #pragma unroll
            for (int u = 0; u < 4; ++u) {
                float e = fmaf(my[u], yj.x, fmaf(mx[u], xj.x, C[u])) + S;
                acc[u] += fast_exp2(e);
            }
        }
    }
    #pragma unroll
    for (int u = 0; u < 4; ++u)
        part[((size_t)t * js + jsp) * N + ibase + u * 256] = acc[u];
}

// K3a: reduce j-split partials -> pdf (/N) + per-(task,chunk) partial sums.
// grid = 10 * 16 blocks; block handles one 256-wide i-chunk of one task.
__global__ void k_reduce(const float* __restrict__ part, float* __restrict__ pdf,
                         float* __restrict__ sums_part, int js) {
    int blk = blockIdx.x;
    int t = blk >> 4;
    int ib = blk & 15;
    int i = ib * 256 + threadIdx.x;
    float s = 0.f;
    for (int q = 0; q < js; ++q) s += part[((size_t)t * js + q) * N + i];
    s *= (1.0f / N);
    pdf[(size_t)t * N + i] = s;
    float tot = block_reduce_sum(s);
    if (threadIdx.x == 0) sums_part[blk] = tot;
}

// K3b: per-combo MI partial. 4 blocks.
__global__ void k_mi2(const float* __restrict__ pdf,
                      const float* __restrict__ sums_part,
                      float* __restrict__ mi) {
    int c = blockIdx.x;
    int b = c >> 1, pr = c & 1;
    int tj = b * 5 + 3 + pr;
    int tx = b * 5;
    int ty = b * 5 + 1 + pr;
    float sj = 0.f, sx = 0.f, sy = 0.f;
    #pragma unroll
    for (int q = 0; q < 16; ++q) {
        sj += sums_part[tj * 16 + q];
        sx += sums_part[tx * 16 + q];
        sy += sums_part[ty * 16 + q];
    }
    float inv_sj = 1.0f / (sj + 1e-10f);
    float inv_sx = 1.0f / (sx + 1e-10f);
    float inv_sy = 1.0f / (sy + 1e-10f);
    float local = 0.f;
    for (int i = threadIdx.x; i < N; i += 256) {
        float pj = pdf[(size_t)tj * N + i] * inv_sj;
        float px = pdf[(size_t)tx * N + i] * inv_sx;
        float py = pdf[(size_t)ty * N + i] * inv_sy;
        float ratio = (pj + 1e-10f) / (px * py + 1e-10f);
        ratio = fminf(fmaxf(ratio, 1e-10f), 1e10f);
        local += pj * __logf(ratio);
    }
    float tot = block_reduce_sum(local);
    if (threadIdx.x == 0) mi[c] = tot;
}

// K4: final. 1 tiny block.
__global__ void k_fin(const float* __restrict__ mi, float* __restrict__ out) {
    if (threadIdx.x == 0)
        out[0] = -((mi[0] + mi[1]) + (mi[2] + mi[3])) * 0.5f;
}

extern "C" void kernel_launch(void* const* d_in, const int* in_sizes, int n_in,
                              void* d_out, int out_size, void* d_ws, size_t ws_size,
                              hipStream_t stream) {
    const float* fused = (const float*)d_in[0];
    const float* s1    = (const float*)d_in[1];
    const float* s2    = (const float*)d_in[2];
    float* out = (float*)d_out;
    float* ws  = (float*)d_ws;

    // ws layout (floats)
    const size_t off_xa   = 0;                         // 6*N*2
    const size_t off_ma   = off_xa + 12 * (size_t)N;   // 6*N*2
    const size_t off_pdf  = off_ma + 12 * (size_t)N;   // 10*N
    const size_t off_sp   = off_pdf + 10 * (size_t)N;  // 160
    const size_t off_mi   = off_sp + 160;              // 16
    const size_t off_part = off_mi + 16;               // 10*js*N

    int js = 16;
    while (js > 1 && (off_part + (size_t)10 * js * N) * 4 > ws_size) js >>= 1;

    float2* ws_xa   = (float2*)(ws + off_xa);
    float2* ws_ma   = (float2*)(ws + off_ma);
    float*  ws_pdf  = ws + off_pdf;
    float*  ws_sp   = ws + off_sp;
    float*  ws_mi   = ws + off_mi;
    float*  ws_part = ws + off_part;

    k_stats<<<dim3(6), dim3(256), 0, stream>>>(fused, s1, s2, ws_xa, ws_ma);
    k_pdf<<<dim3(10 * 4 * js), dim3(256), 0, stream>>>(ws_xa, ws_ma, ws_part, js);
    k_reduce<<<dim3(160), dim3(256), 0, stream>>>(ws_part, ws_pdf, ws_sp, js);
    k_mi2<<<dim3(4), dim3(256), 0, stream>>>(ws_pdf, ws_sp, ws_mi);
    k_fin<<<dim3(1), dim3(64), 0, stream>>>(ws_mi, out);
}

// Round 4
// 48.878 us; speedup vs baseline: 3.3561x; 1.2446x over previous
//
#include <hip/hip_runtime.h>

#define N 4096
#define LOG2E 1.4426950408889634f

__device__ __forceinline__ float fast_exp2(float x) {
#if __has_builtin(__builtin_amdgcn_exp2f)
    return __builtin_amdgcn_exp2f(x);
#else
    return exp2f(x);
#endif
}

__device__ float block_reduce_sum(float v) {
    __shared__ float red[8];
    int lane = threadIdx.x & 63;
    int wid = threadIdx.x >> 6;
    #pragma unroll
    for (int off = 32; off; off >>= 1) v += __shfl_down(v, off, 64);
    if (lane == 0) red[wid] = v;
    __syncthreads();
    if (threadIdx.x == 0) {
        int nw = (int)(blockDim.x >> 6);
        float s = red[0];
        for (int w = 1; w < nw; ++w) s += red[w];
        red[0] = s;
    }
    __syncthreads();
    float r = red[0];
    __syncthreads();
    return r;
}

// K1: per-vector stats + coefficient arrays.
// xa[vec][j] = (x_j, a_j)   (j-side, a = c1*x^2)
// ma[vec][i] = (m_i, a_i)   (i-side, m = -2*c1*x)
__global__ void k_stats(const float* __restrict__ fused,
                        const float* __restrict__ s1,
                        const float* __restrict__ s2,
                        float2* __restrict__ xa,
                        float2* __restrict__ ma) {
    int vec = blockIdx.x;
    int b = vec / 3, k = vec % 3;
    const float* src = (k == 0 ? fused : (k == 1 ? s1 : s2)) + b * 16384;
    int tid = threadIdx.x;
    float v[16];
    float s = 0.f;
    #pragma unroll
    for (int t = 0; t < 16; ++t) { v[t] = src[tid + t * 256]; s += v[t]; }
    float total = block_reduce_sum(s);
    float mean = total * (1.0f / 4096.0f);
    float ssq = 0.f;
    #pragma unroll
    for (int t = 0; t < 16; ++t) { float d = v[t] - mean; ssq += d * d; }
    float tssq = block_reduce_sum(ssq);
    float stdv = sqrtf(tssq / 4095.0f);            // ddof=1
    float sigma = fminf(fmaxf(0.2f * stdv, 0.001f), 1.0f);
    float inv = 1.0f / (stdv + 1e-8f);
    float c1 = -0.5f * LOG2E / (sigma * sigma);
    float2* xav = xa + (size_t)vec * N;
    float2* mav = ma + (size_t)vec * N;
    #pragma unroll
    for (int t = 0; t < 16; ++t) {
        int i = tid + t * 256;
        float x = (v[t] - mean) * inv;
        float a = c1 * x * x;
        xav[i] = make_float2(x, a);
        mav[i] = make_float2(-2.0f * c1 * x, a);
    }
}

// K2: raw kernel-sum partials with LDS-staged j-tiles.
// Tasks t=0..9: t=b*5+p; p<3 marginal of vec b*3+p, p=3: joint(x,y1), p=4: joint(x,y2).
// Each thread owns IB=4 i-values (block covers 1024 i's, nib=4).
// grid = 10 * 4 * js, block 256. j-range split js ways.
__global__ void k_pdf(const float2* __restrict__ xa,
                      const float2* __restrict__ ma,
                      float* __restrict__ part, int js) {
    __shared__ float2 sx[256];
    __shared__ float2 sy[256];
    const int nib = 4;
    int bid = blockIdx.x;
    int t = bid / (nib * js);
    int rem = bid % (nib * js);
    int ib = rem / js, jsp = rem % js;
    int p = t % 5, b = t / 5;
    int jlen = N / js;
    int j0 = jsp * jlen;
    int tid = threadIdx.x;
    int ibase = ib * 1024 + tid;

    float acc[4] = {0.f, 0.f, 0.f, 0.f};

    if (p < 3) {
        int v = b * 3 + p;
        const float2* xav = xa + (size_t)v * N;
        const float2* mav = ma + (size_t)v * N;
        float m[4], ai[4];
        #pragma unroll
        for (int u = 0; u < 4; ++u) {
            float2 q = mav[ibase + u * 256];
            m[u] = q.x; ai[u] = q.y;
        }
        for (int jt = 0; jt < jlen; jt += 256) {
            int cnt = min(256, jlen - jt);
            __syncthreads();
            if (tid < cnt) sx[tid] = xav[j0 + jt + tid];
            __syncthreads();
            #pragma unroll 4
            for (int j = 0; j < cnt; ++j) {
                float2 xj = sx[j];
                #pragma unroll
                for (int u = 0; u < 4; ++u)
                    acc[u] += fast_exp2(fmaf(m[u], xj.x, ai[u]) + xj.y);
            }
        }
    } else {
        int vx = b * 3, vy = b * 3 + (p - 2);
        const float2* xav = xa + (size_t)vx * N;
        const float2* yav = xa + (size_t)vy * N;
        const float2* mxv = ma + (size_t)vx * N;
        const float2* myv = ma + (size_t)vy * N;
        float mx[4], my[4], C[4];
        #pragma unroll
        for (int u = 0; u < 4; ++u) {
            float2 qx = mxv[ibase + u * 256];
            float2 qy = myv[ibase + u * 256];
            mx[u] = qx.x; my[u] = qy.x; C[u] = qx.y + qy.y;
        }
        for (int jt = 0; jt < jlen; jt += 256) {
            int cnt = min(256, jlen - jt);
            __syncthreads();
            if (tid < cnt) {
                float2 xq = xav[j0 + jt + tid];
                float2 yq = yav[j0 + jt + tid];
                sx[tid] = xq;
                sy[tid] = make_float2(yq.x, xq.y + yq.y);  // (y_j, S_j)
            }
            __syncthreads();
            #pragma unroll 4
            for (int j = 0; j < cnt; ++j) {
                float2 xj = sx[j];
                float2 yj = sy[j];
                #pragma unroll
                for (int u = 0; u < 4; ++u) {
                    float e = fmaf(my[u], yj.x, fmaf(mx[u], xj.x, C[u])) + yj.y;
                    acc[u] += fast_exp2(e);
                }
            }
        }
    }
    #pragma unroll
    for (int u = 0; u < 4; ++u)
        part[((size_t)t * js + jsp) * N + ibase + u * 256] = acc[u];
}

// K3a: reduce j-split partials -> pdf (/N) + per-(task,chunk) partial sums.
// grid = 10 * 16 blocks; block handles one 256-wide i-chunk of one task.
__global__ void k_reduce(const float* __restrict__ part, float* __restrict__ pdf,
                         float* __restrict__ sums_part, int js) {
    int blk = blockIdx.x;
    int t = blk >> 4;
    int ib = blk & 15;
    int i = ib * 256 + threadIdx.x;
    float s = 0.f;
    for (int q = 0; q < js; ++q) s += part[((size_t)t * js + q) * N + i];
    s *= (1.0f / N);
    pdf[(size_t)t * N + i] = s;
    float tot = block_reduce_sum(s);
    if (threadIdx.x == 0) sums_part[blk] = tot;
}

// K3b: per-(combo, i-chunk) MI partial. 64 blocks.
__global__ void k_mi2(const float* __restrict__ pdf,
                      const float* __restrict__ sums_part,
                      float* __restrict__ mi_part) {
    int blk = blockIdx.x;
    int c = blk >> 4;
    int ic = blk & 15;
    int b = c >> 1, pr = c & 1;
    int tj = b * 5 + 3 + pr;
    int tx = b * 5;
    int ty = b * 5 + 1 + pr;
    float sj = 0.f, sx = 0.f, sy = 0.f;
    #pragma unroll
    for (int q = 0; q < 16; ++q) {
        sj += sums_part[tj * 16 + q];
        sx += sums_part[tx * 16 + q];
        sy += sums_part[ty * 16 + q];
    }
    float inv_sj = 1.0f / (sj + 1e-10f);
    float inv_sx = 1.0f / (sx + 1e-10f);
    float inv_sy = 1.0f / (sy + 1e-10f);
    int i = ic * 256 + threadIdx.x;
    float pj = pdf[(size_t)tj * N + i] * inv_sj;
    float px = pdf[(size_t)tx * N + i] * inv_sx;
    float py = pdf[(size_t)ty * N + i] * inv_sy;
    float ratio = (pj + 1e-10f) / (px * py + 1e-10f);
    ratio = fminf(fmaxf(ratio, 1e-10f), 1e10f);
    float local = pj * __logf(ratio);
    float tot = block_reduce_sum(local);
    if (threadIdx.x == 0) mi_part[blk] = tot;
}

// K4: final. 1 block, 64 threads (1 wave).
__global__ void k_fin(const float* __restrict__ mi_part, float* __restrict__ out) {
    float v = mi_part[threadIdx.x];  // 64 entries
    #pragma unroll
    for (int off = 32; off; off >>= 1) v += __shfl_down(v, off, 64);
    if (threadIdx.x == 0) out[0] = -v * 0.5f;
}

extern "C" void kernel_launch(void* const* d_in, const int* in_sizes, int n_in,
                              void* d_out, int out_size, void* d_ws, size_t ws_size,
                              hipStream_t stream) {
    const float* fused = (const float*)d_in[0];
    const float* s1    = (const float*)d_in[1];
    const float* s2    = (const float*)d_in[2];
    float* out = (float*)d_out;
    float* ws  = (float*)d_ws;

    // ws layout (floats)
    const size_t off_xa   = 0;                         // 6*N*2
    const size_t off_ma   = off_xa + 12 * (size_t)N;   // 6*N*2
    const size_t off_pdf  = off_ma + 12 * (size_t)N;   // 10*N
    const size_t off_sp   = off_pdf + 10 * (size_t)N;  // 160
    const size_t off_mi   = off_sp + 160;              // 64
    const size_t off_part = off_mi + 64;               // 10*js*N

    int js = 32;
    while (js > 1 && (off_part + (size_t)10 * js * N) * 4 > ws_size) js >>= 1;

    float2* ws_xa   = (float2*)(ws + off_xa);
    float2* ws_ma   = (float2*)(ws + off_ma);
    float*  ws_pdf  = ws + off_pdf;
    float*  ws_sp   = ws + off_sp;
    float*  ws_mi   = ws + off_mi;
    float*  ws_part = ws + off_part;

    k_stats<<<dim3(6), dim3(256), 0, stream>>>(fused, s1, s2, ws_xa, ws_ma);
    k_pdf<<<dim3(10 * 4 * js), dim3(256), 0, stream>>>(ws_xa, ws_ma, ws_part, js);
    k_reduce<<<dim3(160), dim3(256), 0, stream>>>(ws_part, ws_pdf, ws_sp, js);
    k_mi2<<<dim3(64), dim3(256), 0, stream>>>(ws_pdf, ws_sp, ws_mi);
    k_fin<<<dim3(1), dim3(64), 0, stream>>>(ws_mi, out);
}

// Round 5
// 48.796 us; speedup vs baseline: 3.3618x; 1.0017x over previous
//
#include <hip/hip_runtime.h>

#define N 4096
#define LOG2E 1.4426950408889634f

__device__ __forceinline__ float fast_exp2(float x) {
#if __has_builtin(__builtin_amdgcn_exp2f)
    return __builtin_amdgcn_exp2f(x);
#else
    return exp2f(x);
#endif
}

// float2 helpers -> v_pk_fma_f32 / v_pk_add_f32 (full-rate packed fp32 on CDNA)
__device__ __forceinline__ float2 f2fma(float2 a, float s, float2 c) {
    return make_float2(fmaf(a.x, s, c.x), fmaf(a.y, s, c.y));
}
__device__ __forceinline__ float2 f2adds(float2 a, float s) {
    return make_float2(a.x + s, a.y + s);
}
__device__ __forceinline__ float2 f2addv(float2 a, float2 b) {
    return make_float2(a.x + b.x, a.y + b.y);
}

__device__ float block_reduce_sum(float v) {
    __shared__ float red[8];
    int lane = threadIdx.x & 63;
    int wid = threadIdx.x >> 6;
    #pragma unroll
    for (int off = 32; off; off >>= 1) v += __shfl_down(v, off, 64);
    if (lane == 0) red[wid] = v;
    __syncthreads();
    if (threadIdx.x == 0) {
        int nw = (int)(blockDim.x >> 6);
        float s = red[0];
        for (int w = 1; w < nw; ++w) s += red[w];
        red[0] = s;
    }
    __syncthreads();
    float r = red[0];
    __syncthreads();
    return r;
}

// K1: per-vector stats + coefficient arrays.
// xa[vec][j] = (x_j, a_j)   (j-side, a = c1*x^2)
// ma[vec][i] = (m_i, a_i)   (i-side, m = -2*c1*x)
__global__ void k_stats(const float* __restrict__ fused,
                        const float* __restrict__ s1,
                        const float* __restrict__ s2,
                        float2* __restrict__ xa,
                        float2* __restrict__ ma) {
    int vec = blockIdx.x;
    int b = vec / 3, k = vec % 3;
    const float* src = (k == 0 ? fused : (k == 1 ? s1 : s2)) + b * 16384;
    int tid = threadIdx.x;
    float v[16];
    float s = 0.f;
    #pragma unroll
    for (int t = 0; t < 16; ++t) { v[t] = src[tid + t * 256]; s += v[t]; }
    float total = block_reduce_sum(s);
    float mean = total * (1.0f / 4096.0f);
    float ssq = 0.f;
    #pragma unroll
    for (int t = 0; t < 16; ++t) { float d = v[t] - mean; ssq += d * d; }
    float tssq = block_reduce_sum(ssq);
    float stdv = sqrtf(tssq / 4095.0f);            // ddof=1
    float sigma = fminf(fmaxf(0.2f * stdv, 0.001f), 1.0f);
    float inv = 1.0f / (stdv + 1e-8f);
    float c1 = -0.5f * LOG2E / (sigma * sigma);
    float2* xav = xa + (size_t)vec * N;
    float2* mav = ma + (size_t)vec * N;
    #pragma unroll
    for (int t = 0; t < 16; ++t) {
        int i = tid + t * 256;
        float x = (v[t] - mean) * inv;
        float a = c1 * x * x;
        xav[i] = make_float2(x, a);
        mav[i] = make_float2(-2.0f * c1 * x, a);
    }
}

// K2: raw kernel-sum partials. LDS-staged j-range (tiles of 128), packed-fp32
// inner loop with paired accumulators.
// Tasks t=0..9: t=b*5+p; p<3 marginal of vec b*3+p, p=3: joint(x,y1), p=4: joint(x,y2).
// Each thread owns IB=4 i-values (block covers 1024 i's, nib=4).
// grid = 10 * 4 * js, block 256.
__global__ void k_pdf(const float2* __restrict__ xa,
                      const float2* __restrict__ ma,
                      float* __restrict__ part, int js) {
    __shared__ float2 sm2[128];   // marginal: (x_j, a_j)
    __shared__ float4 sm4[128];   // joint:    (x_j, y_j, S_j, -)
    const int nib = 4;
    int bid = blockIdx.x;
    int t = bid / (nib * js);
    int rem = bid % (nib * js);
    int ib = rem / js, jsp = rem % js;
    int p = t % 5, b = t / 5;
    int jlen = N / js;
    int j0 = jsp * jlen;
    int tid = threadIdx.x;
    int ibase = ib * 1024 + tid;

    float2 acc01 = make_float2(0.f, 0.f);
    float2 acc23 = make_float2(0.f, 0.f);

    if (p < 3) {
        int v = b * 3 + p;
        const float2* xav = xa + (size_t)v * N;
        const float2* mav = ma + (size_t)v * N;
        float2 q0 = mav[ibase];
        float2 q1 = mav[ibase + 256];
        float2 q2 = mav[ibase + 512];
        float2 q3 = mav[ibase + 768];
        float2 m01 = make_float2(q0.x, q1.x), m23 = make_float2(q2.x, q3.x);
        float2 a01 = make_float2(q0.y, q1.y), a23 = make_float2(q2.y, q3.y);
        for (int jt = 0; jt < jlen; jt += 128) {
            int cnt = min(128, jlen - jt);
            __syncthreads();
            if (tid < cnt) sm2[tid] = xav[j0 + jt + tid];
            __syncthreads();
            #pragma unroll 4
            for (int j = 0; j < cnt; ++j) {
                float2 xj = sm2[j];
                float2 e01 = f2fma(m01, xj.x, f2adds(a01, xj.y));
                float2 e23 = f2fma(m23, xj.x, f2adds(a23, xj.y));
                acc01 = f2addv(acc01, make_float2(fast_exp2(e01.x), fast_exp2(e01.y)));
                acc23 = f2addv(acc23, make_float2(fast_exp2(e23.x), fast_exp2(e23.y)));
            }
        }
    } else {
        int vx = b * 3, vy = b * 3 + (p - 2);
        const float2* xav = xa + (size_t)vx * N;
        const float2* yav = xa + (size_t)vy * N;
        const float2* mxv = ma + (size_t)vx * N;
        const float2* myv = ma + (size_t)vy * N;
        float2 qx0 = mxv[ibase],       qy0 = myv[ibase];
        float2 qx1 = mxv[ibase + 256], qy1 = myv[ibase + 256];
        float2 qx2 = mxv[ibase + 512], qy2 = myv[ibase + 512];
        float2 qx3 = mxv[ibase + 768], qy3 = myv[ibase + 768];
        float2 mx01 = make_float2(qx0.x, qx1.x), mx23 = make_float2(qx2.x, qx3.x);
        float2 my01 = make_float2(qy0.x, qy1.x), my23 = make_float2(qy2.x, qy3.x);
        float2 C01 = make_float2(qx0.y + qy0.y, qx1.y + qy1.y);
        float2 C23 = make_float2(qx2.y + qy2.y, qx3.y + qy3.y);
        for (int jt = 0; jt < jlen; jt += 128) {
            int cnt = min(128, jlen - jt);
            __syncthreads();
            if (tid < cnt) {
                float2 xq = xav[j0 + jt + tid];
                float2 yq = yav[j0 + jt + tid];
                sm4[tid] = make_float4(xq.x, yq.x, xq.y + yq.y, 0.f);
            }
            __syncthreads();
            #pragma unroll 4
            for (int j = 0; j < cnt; ++j) {
                float4 qj = sm4[j];
                float2 e01 = f2fma(my01, qj.y, f2fma(mx01, qj.x, f2adds(C01, qj.z)));
                float2 e23 = f2fma(my23, qj.y, f2fma(mx23, qj.x, f2adds(C23, qj.z)));
                acc01 = f2addv(acc01, make_float2(fast_exp2(e01.x), fast_exp2(e01.y)));
                acc23 = f2addv(acc23, make_float2(fast_exp2(e23.x), fast_exp2(e23.y)));
            }
        }
    }
    float* dst = part + ((size_t)t * js + jsp) * N + ibase;
    dst[0]   = acc01.x;
    dst[256] = acc01.y;
    dst[512] = acc23.x;
    dst[768] = acc23.y;
}

// K3a: reduce j-split partials -> pdf (/N) + per-(task,chunk) partial sums.
// grid = 10 * 16 blocks; block handles one 256-wide i-chunk of one task.
__global__ void k_reduce(const float* __restrict__ part, float* __restrict__ pdf,
                         float* __restrict__ sums_part, int js) {
    int blk = blockIdx.x;
    int t = blk >> 4;
    int ib = blk & 15;
    int i = ib * 256 + threadIdx.x;
    float s = 0.f;
    for (int q = 0; q < js; ++q) s += part[((size_t)t * js + q) * N + i];
    s *= (1.0f / N);
    pdf[(size_t)t * N + i] = s;
    float tot = block_reduce_sum(s);
    if (threadIdx.x == 0) sums_part[blk] = tot;
}

// K3b: per-(combo, i-chunk) MI partial. 64 blocks.
__global__ void k_mi2(const float* __restrict__ pdf,
                      const float* __restrict__ sums_part,
                      float* __restrict__ mi_part) {
    int blk = blockIdx.x;
    int c = blk >> 4;
    int ic = blk & 15;
    int b = c >> 1, pr = c & 1;
    int tj = b * 5 + 3 + pr;
    int tx = b * 5;
    int ty = b * 5 + 1 + pr;
    float sj = 0.f, sx = 0.f, sy = 0.f;
    #pragma unroll
    for (int q = 0; q < 16; ++q) {
        sj += sums_part[tj * 16 + q];
        sx += sums_part[tx * 16 + q];
        sy += sums_part[ty * 16 + q];
    }
    float inv_sj = 1.0f / (sj + 1e-10f);
    float inv_sx = 1.0f / (sx + 1e-10f);
    float inv_sy = 1.0f / (sy + 1e-10f);
    int i = ic * 256 + threadIdx.x;
    float pj = pdf[(size_t)tj * N + i] * inv_sj;
    float px = pdf[(size_t)tx * N + i] * inv_sx;
    float py = pdf[(size_t)ty * N + i] * inv_sy;
    float ratio = (pj + 1e-10f) / (px * py + 1e-10f);
    ratio = fminf(fmaxf(ratio, 1e-10f), 1e10f);
    float local = pj * __logf(ratio);
    float tot = block_reduce_sum(local);
    if (threadIdx.x == 0) mi_part[blk] = tot;
}

// K4: final. 1 block, 64 threads (1 wave).
__global__ void k_fin(const float* __restrict__ mi_part, float* __restrict__ out) {
    float v = mi_part[threadIdx.x];  // 64 entries
    #pragma unroll
    for (int off = 32; off; off >>= 1) v += __shfl_down(v, off, 64);
    if (threadIdx.x == 0) out[0] = -v * 0.5f;
}

extern "C" void kernel_launch(void* const* d_in, const int* in_sizes, int n_in,
                              void* d_out, int out_size, void* d_ws, size_t ws_size,
                              hipStream_t stream) {
    const float* fused = (const float*)d_in[0];
    const float* s1    = (const float*)d_in[1];
    const float* s2    = (const float*)d_in[2];
    float* out = (float*)d_out;
    float* ws  = (float*)d_ws;

    // ws layout (floats)
    const size_t off_xa   = 0;                         // 6*N*2
    const size_t off_ma   = off_xa + 12 * (size_t)N;   // 6*N*2
    const size_t off_pdf  = off_ma + 12 * (size_t)N;   // 10*N
    const size_t off_sp   = off_pdf + 10 * (size_t)N;  // 160
    const size_t off_mi   = off_sp + 160;              // 64
    const size_t off_part = off_mi + 64;               // 10*js*N

    int js = 32;
    while (js > 1 && (off_part + (size_t)10 * js * N) * 4 > ws_size) js >>= 1;

    float2* ws_xa   = (float2*)(ws + off_xa);
    float2* ws_ma   = (float2*)(ws + off_ma);
    float*  ws_pdf  = ws + off_pdf;
    float*  ws_sp   = ws + off_sp;
    float*  ws_mi   = ws + off_mi;
    float*  ws_part = ws + off_part;

    k_stats<<<dim3(6), dim3(256), 0, stream>>>(fused, s1, s2, ws_xa, ws_ma);
    k_pdf<<<dim3(10 * 4 * js), dim3(256), 0, stream>>>(ws_xa, ws_ma, ws_part, js);
    k_reduce<<<dim3(160), dim3(256), 0, stream>>>(ws_part, ws_pdf, ws_sp, js);
    k_mi2<<<dim3(64), dim3(256), 0, stream>>>(ws_pdf, ws_sp, ws_mi);
    k_fin<<<dim3(1), dim3(64), 0, stream>>>(ws_mi, out);
}